// Round 14
// baseline (152.909 us; speedup 1.0000x reference)
//
#include <hip/hip_runtime.h>
#include <math.h>

// ---------------- problem constants ----------------
#define BATCH   16
#define T_LEN   262144
#define NB      16          // biquad stages
#define L       64          // samples per chunk
#define GRP     64          // chunks per group (== wave width)
#define SUB     8           // chunks per sub-group (chain depth)
#define NSUB    512         // sub-groups per batch
#define NSUP    32          // super-groups per batch (sup = 16 subs = 8192 smp)
#define NG      64          // groups (waves) per batch
#define NCHUNK  4096        // chunks per batch
#define XSTRIDE 68          // LDS audio row stride (64 + 4 pad)

#define DPI 3.14159265358979323846264338327950288

// ---------------- ws layout (floats) ----------------
#define OFF_COEF  0          // [16][96]
#define OFF_A64   1536       // [16][32][32]  A^64    (f32, f64-computed)
#define OFF_A512  17920      // [16][32][32]  A^512
#define OFF_A8K   34304      // [16][32][32]  A^8192
#define OFF_QEND  50688      // [16][512][32] zero-init sub-group totals
#define OFF_SARR  312832     // [16][512][32] sub-group start states
#define OFF_P     574976     // [16][64][32][64] chunk-final states, transposed
// total = 574976 + 16*64*2048 = 2,672,128 floats ~= 10.7 MB

// ---------------- stage coefficient math (f64) ----------------
__device__ inline void stage_coefs(int i, double fn, double gn, double qn,
                                   double& B0, double& B1, double& B2,
                                   double& A1, double& A2) {
    const double FS = 96000.0;
    double Q    = exp(log(0.5) + qn * (log(16.0) - log(0.5)));
    double gain = -24.0 + gn * 48.0;
    double lo, hi;
    if (i == 0)            { lo = 20.0;   hi = 500.0;   }
    else if (i == 15)      { lo = 5000.0; hi = 20000.0; }
    else if (i == 1 || i == 14) { lo = 50.0; hi = 16000.0; }
    else                   { lo = 100.0;  hi = 15000.0; }
    double fc    = exp(log(lo) + fn * (log(hi) - log(lo)));
    double w0    = 2.0 * DPI * fc / FS;
    double alpha = sin(w0) / (2.0 * Q);
    double c     = cos(w0);
    double b0, b1, b2, a0, a1, a2;
    if (i == 0) {
        b0 = (1.0 + c) * 0.5; b1 = -(1.0 + c); b2 = (1.0 + c) * 0.5;
        a0 = 1.0 + alpha; a1 = -2.0 * c; a2 = 1.0 - alpha;
    } else if (i == 15) {
        b0 = (1.0 - c) * 0.5; b1 = 1.0 - c; b2 = (1.0 - c) * 0.5;
        a0 = 1.0 + alpha; a1 = -2.0 * c; a2 = 1.0 - alpha;
    } else if (i == 1) {
        double A = pow(10.0, gain / 40.0), sA = sqrt(A);
        b0 = A * ((A + 1.0) - (A - 1.0) * c + 2.0 * sA * alpha);
        b1 = 2.0 * A * ((A - 1.0) - (A + 1.0) * c);
        b2 = A * ((A + 1.0) - (A - 1.0) * c - 2.0 * sA * alpha);
        a0 = (A + 1.0) + (A - 1.0) * c + 2.0 * sA * alpha;
        a1 = -2.0 * ((A - 1.0) + (A + 1.0) * c);
        a2 = (A + 1.0) + (A - 1.0) * c - 2.0 * sA * alpha;
    } else if (i == 14) {
        double A = pow(10.0, gain / 40.0), sA = sqrt(A);
        b0 = A * ((A + 1.0) + (A - 1.0) * c + 2.0 * sA * alpha);
        b1 = -2.0 * A * ((A - 1.0) + (A + 1.0) * c);
        b2 = A * ((A + 1.0) + (A - 1.0) * c - 2.0 * sA * alpha);
        a0 = (A + 1.0) - (A - 1.0) * c + 2.0 * sA * alpha;
        a1 = 2.0 * ((A - 1.0) - (A + 1.0) * c);
        a2 = (A + 1.0) - (A - 1.0) * c - 2.0 * sA * alpha;
    } else {
        double A = pow(10.0, gain / 40.0);
        b0 = 1.0 + alpha * A; b1 = -2.0 * c; b2 = 1.0 - alpha * A;
        a0 = 1.0 + alpha / A; a1 = -2.0 * c; a2 = 1.0 - alpha / A;
    }
    B0 = b0 / a0; B1 = b1 / a0; B2 = b2 / a0; A1 = a1 / a0; A2 = a2 / a0;
}

// ---------------- K0: coefs + A^64 / A^512 / A^8192 (f64) -------------------
// f64 REQUIRED: intermediate powers of the non-normal cascade matrix
// transiently exceed f32 range (round-6 f32 chain -> Inf -> NaN).
__global__ __launch_bounds__(256) void k0_setup(const float* __restrict__ params,
                                                float* __restrict__ coefs,
                                                float* __restrict__ A64,
                                                float* __restrict__ A512,
                                                float* __restrict__ A8K) {
    int b = blockIdx.x;
    int t = threadIdx.x;
    __shared__ double cf[NB][5];
    __shared__ double M1[32 * 32];
    __shared__ double M2[32 * 32];

    if (t < NB) {
        double B0, B1, B2, A1, A2;
        stage_coefs(t, (double)params[b * 50 + t * 3 + 0],
                       (double)params[b * 50 + t * 3 + 1],
                       (double)params[b * 50 + t * 3 + 2], B0, B1, B2, A1, A2);
        float f0 = (float)B0, f1 = (float)B1, f2 = (float)B2, f3 = (float)A1, f4 = (float)A2;
        cf[t][0] = (double)f0; cf[t][1] = (double)f1; cf[t][2] = (double)f2;
        cf[t][3] = (double)f3; cf[t][4] = (double)f4;
        float* cp = coefs + b * 96 + t * 5;
        cp[0] = f0; cp[1] = f1; cp[2] = f2; cp[3] = f3; cp[4] = f4;
    }
    if (t == NB) {
        double indb = -60.0 + (double)params[b * 50 + 48] * 60.0;
        coefs[b * 96 + 80] = (float)pow(10.0, indb / 20.0);
    }
    if (t == NB + 1) {
        double outdb = -60.0 + (double)params[b * 50 + 49] * 60.0;
        coefs[b * 96 + 81] = (float)pow(10.0, outdb / 20.0);
    }
    __syncthreads();

    if (t < 32) {
        double s1[NB], s2[NB];
#pragma unroll
        for (int i = 0; i < NB; i++) {
            s1[i] = (t == 2 * i) ? 1.0 : 0.0;
            s2[i] = (t == 2 * i + 1) ? 1.0 : 0.0;
        }
        double u = 0.0;
#pragma unroll
        for (int i = 0; i < NB; i++) {
            double y  = cf[i][0] * u + s1[i];
            double n1 = cf[i][1] * u - cf[i][3] * y + s2[i];
            double n2 = cf[i][2] * u - cf[i][4] * y;
            s1[i] = n1; s2[i] = n2; u = y;
        }
#pragma unroll
        for (int i = 0; i < NB; i++) {
            M1[(2 * i) * 32 + t]     = s1[i];
            M1[(2 * i + 1) * 32 + t] = s2[i];
        }
    }
    __syncthreads();

    // 13 squarings; save A^64 (sq=5), A^512 (sq=8), A^8192 (sq=12).
    // thread t: column c=t&31, rows r0+{0,8,16,24}; conflict-free (m136).
    int c  = t & 31;
    int r0 = t >> 5;
    double* src = M1;
    double* dst = M2;
    for (int sq = 0; sq < 13; sq++) {
        double acc[4] = {0.0, 0.0, 0.0, 0.0};
        for (int k = 0; k < 32; k++) {
            double bv = src[k * 32 + c];
#pragma unroll
            for (int e = 0; e < 4; e++)
                acc[e] += src[(e * 8 + r0) * 32 + k] * bv;
        }
#pragma unroll
        for (int e = 0; e < 4; e++) dst[(e * 8 + r0) * 32 + c] = acc[e];
        __syncthreads();
        { double* tmp = src; src = dst; dst = tmp; }
        float* out_m = (sq == 5) ? A64 : (sq == 8) ? A512 : (sq == 12) ? A8K : nullptr;
        if (out_m) {
#pragma unroll
            for (int e = 0; e < 4; e++) {
                int idx = (e * 8 + r0) * 32 + c;
                out_m[b * 1024 + idx] = (float)src[idx];
            }
        }
        __syncthreads();
    }
}

// ---------------- LDS-broadcast matvec step, 4 dual-half slots --------------
// Publishes the 4 chain q-vectors (this half's chains cb..cb+3) to qldsw,
// then every lane reads them back via uniform-address ds_read_b128 (hardware
// broadcast; 2 addrs/inst across halves = 2-way alias = free). qb lands in
// VGPRs -> plain v_fma, NO v_readlane SGPR-write hazards. Even/odd dual
// accumulators match the previous readlane step's summation order exactly.
__device__ __forceinline__ void bc_step4(float* qldsw, int row, int cb,
                                         const float* ar,
                                         float p0, float p1, float p2, float p3,
                                         float& q0, float& q1, float& q2, float& q3) {
    qldsw[(cb + 0) * 32 + row] = q0;
    qldsw[(cb + 1) * 32 + row] = q1;
    qldsw[(cb + 2) * 32 + row] = q2;
    qldsw[(cb + 3) * 32 + row] = q3;
    const float* qb = qldsw + cb * 32;
    float a0 = p0, b0 = 0.f, a1 = p1, b1 = 0.f;
    float a2 = p2, b2 = 0.f, a3 = p3, b3 = 0.f;
#pragma unroll
    for (int t4 = 0; t4 < 8; t4++) {
        float4 v0 = *(const float4*)(qb + 0 * 32 + 4 * t4);
        float4 v1 = *(const float4*)(qb + 1 * 32 + 4 * t4);
        float4 v2 = *(const float4*)(qb + 2 * 32 + 4 * t4);
        float4 v3 = *(const float4*)(qb + 3 * 32 + 4 * t4);
        a0 = fmaf(ar[4 * t4 + 0], v0.x, a0); b0 = fmaf(ar[4 * t4 + 1], v0.y, b0);
        a0 = fmaf(ar[4 * t4 + 2], v0.z, a0); b0 = fmaf(ar[4 * t4 + 3], v0.w, b0);
        a1 = fmaf(ar[4 * t4 + 0], v1.x, a1); b1 = fmaf(ar[4 * t4 + 1], v1.y, b1);
        a1 = fmaf(ar[4 * t4 + 2], v1.z, a1); b1 = fmaf(ar[4 * t4 + 3], v1.w, b1);
        a2 = fmaf(ar[4 * t4 + 0], v2.x, a2); b2 = fmaf(ar[4 * t4 + 1], v2.y, b2);
        a2 = fmaf(ar[4 * t4 + 2], v2.z, a2); b2 = fmaf(ar[4 * t4 + 3], v2.w, b2);
        a3 = fmaf(ar[4 * t4 + 0], v3.x, a3); b3 = fmaf(ar[4 * t4 + 1], v3.y, b3);
        a3 = fmaf(ar[4 * t4 + 2], v3.z, a3); b3 = fmaf(ar[4 * t4 + 3], v3.w, b3);
    }
    q0 = a0 + b0; q1 = a1 + b1; q2 = a2 + b2; q3 = a3 + b3;
}

// readlane step (kept only for k2's tiny 32-step super scan)
__device__ __forceinline__ float mv_step_rl(const float* ar, float q, float addv) {
    int qi = __float_as_int(q);
    float qb[32];
#pragma unroll
    for (int t = 0; t < 32; t++)
        qb[t] = __int_as_float(__builtin_amdgcn_readlane(qi, t));
    float acc0 = addv, acc1 = 0.f;
#pragma unroll
    for (int t = 0; t < 32; t += 2) {
        acc0 = fmaf(ar[t], qb[t], acc0);
        acc1 = fmaf(ar[t + 1], qb[t + 1], acc1);
    }
    return acc0 + acc1;
}

__device__ __forceinline__ void load_row32(const float* base, int row, float* ar) {
    const float4* a4 = (const float4*)(base + row * 32);
#pragma unroll
    for (int j = 0; j < 8; j++) {
        float4 v = a4[j];
        ar[4 * j + 0] = v.x; ar[4 * j + 1] = v.y;
        ar[4 * j + 2] = v.z; ar[4 * j + 3] = v.w;
    }
}

// Coalesced audio stage (16 KB wave footprint -> LDS [chunk][68])
__device__ __forceinline__ void stage_audio(const float* __restrict__ gbase,
                                            float* __restrict__ xlds, int lane) {
    const float4* g4 = (const float4*)gbase;
    float4 v[16];
#pragma unroll
    for (int it = 0; it < 16; it++) v[it] = g4[it * 64 + lane];
#pragma unroll
    for (int it = 0; it < 16; it++) {
        int idx = it * 64 + lane;
        int ch = idx >> 4, q = idx & 15;
        *(float4*)&xlds[ch * XSTRIDE + q * 4] = v[it];
    }
}

// ---------------- K1: zero-init chunk states + sub-group totals -------------
__global__ __launch_bounds__(64, 1) void k1_pass1(const float* __restrict__ audio,
                                                  const float* __restrict__ coefs,
                                                  const float* __restrict__ A64,
                                                  float* __restrict__ P,
                                                  float* __restrict__ Qend) {
    int blk   = blockIdx.x;          // 0..1023
    int batch = blk >> 6;
    int grp   = blk & 63;
    int lane  = threadIdx.x;
    int row   = lane & 31;
    int half  = lane >> 5;

    __shared__ float xlds[GRP * XSTRIDE];   // 17.4 KB
    __shared__ float plds[GRP][33];         //  8.4 KB
    __shared__ float qlds[8 * 32];          //  1 KB

    stage_audio(audio + (size_t)batch * T_LEN + (size_t)grp * GRP * L, xlds, lane);
    __syncthreads();

    const float* cf = coefs + batch * 96;
    float c0[NB], c1[NB], c2[NB], c3[NB], c4[NB];
#pragma unroll
    for (int i = 0; i < NB; i++) {
        c0[i] = cf[i * 5 + 0]; c1[i] = cf[i * 5 + 1]; c2[i] = cf[i * 5 + 2];
        c3[i] = cf[i * 5 + 3]; c4[i] = cf[i * 5 + 4];
    }
    float ing = cf[80];

    float s1[NB], s2[NB];
#pragma unroll
    for (int i = 0; i < NB; i++) { s1[i] = 0.f; s2[i] = 0.f; }

    float* xrow = &xlds[lane * XSTRIDE];
#pragma unroll 1
    for (int tt = 0; tt < 16; tt++) {
        float4 xv = *(const float4*)&xrow[tt * 4];
        float xs[4] = {xv.x, xv.y, xv.z, xv.w};
#pragma unroll
        for (int j = 0; j < 4; j++) {
            float u = ing * xs[j];
#pragma unroll
            for (int i = 0; i < NB; i++) {
                float y  = fmaf(c0[i], u, s1[i]);
                float n1 = fmaf(c1[i], u, s2[i]); n1 = fmaf(-c3[i], y, n1);
                float n2 = c2[i] * u;             n2 = fmaf(-c4[i], y, n2);
                s1[i] = n1; s2[i] = n2; u = y;
            }
        }
    }

    // P write: transposed layout P[grp][state][chunk] -> 32 coalesced stores
    {
        float* pb = P + ((size_t)(batch * NG + grp)) * 2048;
#pragma unroll
        for (int i = 0; i < NB; i++) {
            pb[(2 * i) * 64 + lane]     = s1[i];
            pb[(2 * i + 1) * 64 + lane] = s2[i];
        }
    }

#pragma unroll
    for (int i = 0; i < NB; i++) {
        plds[lane][2 * i]     = s1[i];
        plds[lane][2 * i + 1] = s2[i];
    }
    __syncthreads();

    // 8 chains of depth 8, packed as 4 dual-half slots (lanes<32: chains
    // 0-3, lanes>=32: chains 4-7). First step is q = p[0] exactly.
    float ar[32];
    load_row32(A64 + batch * 1024, row, ar);
    int cb = half * 4;
    float q0 = plds[(cb + 0) * SUB][row];
    float q1 = plds[(cb + 1) * SUB][row];
    float q2 = plds[(cb + 2) * SUB][row];
    float q3 = plds[(cb + 3) * SUB][row];
#pragma unroll 1
    for (int j = 1; j < SUB; j++) {
        float p0 = plds[(cb + 0) * SUB + j][row];
        float p1 = plds[(cb + 1) * SUB + j][row];
        float p2 = plds[(cb + 2) * SUB + j][row];
        float p3 = plds[(cb + 3) * SUB + j][row];
        bc_step4(qlds, row, cb, ar, p0, p1, p2, p3, q0, q1, q2, q3);
    }
    {
        float* qe = Qend + ((size_t)(batch * NSUB + grp * 8 + cb)) * 32 + row;
        qe[0] = q0; qe[32] = q1; qe[64] = q2; qe[96] = q3;   // all 64 lanes
    }
}

// ---------------- K2: full hierarchical combine, one block per batch --------
// C1: 32 sup-chains (4 waves x 4 dual-half slots x depth 16, A^512);
// C2: wave-0 scan of 32 supers (A^8192, readlane); C3: seeded sub-scans.
__global__ __launch_bounds__(256, 1) void k2_combine(const float* __restrict__ A512,
                                                     const float* __restrict__ A8K,
                                                     const float* __restrict__ Qend,
                                                     float* __restrict__ Sarr) {
    int batch = blockIdx.x;
    int tid   = threadIdx.x;
    int wave  = tid >> 6;
    int lane  = tid & 63;
    int row   = lane & 31;
    int half  = lane >> 5;
    int cb    = half * 4;

    __shared__ float qe[NSUB][32];          // 64 KB
    __shared__ float qs[NSUP][32];
    __shared__ float ss[NSUP][32];
    __shared__ float qlds[4][8 * 32];       // per-wave broadcast buffers

    {
        const float4* src4 = (const float4*)(Qend + (size_t)batch * NSUB * 32);
        float4* dst4 = (float4*)&qe[0][0];
        for (int i = tid; i < NSUB * 32 / 4; i += 256) dst4[i] = src4[i];
    }
    float ar512[32];
    load_row32(A512 + batch * 1024, row, ar512);
    __syncthreads();

    int sbase = wave * 8 + cb;   // this half's first sup (8 sups per wave)

    // C1: chains over 16 subs per sup (first step = qe[s*16+0] exactly)
    {
        float q0 = qe[(sbase + 0) * 16][row];
        float q1 = qe[(sbase + 1) * 16][row];
        float q2 = qe[(sbase + 2) * 16][row];
        float q3 = qe[(sbase + 3) * 16][row];
#pragma unroll 1
        for (int j = 1; j < 16; j++) {
            float p0 = qe[(sbase + 0) * 16 + j][row];
            float p1 = qe[(sbase + 1) * 16 + j][row];
            float p2 = qe[(sbase + 2) * 16 + j][row];
            float p3 = qe[(sbase + 3) * 16 + j][row];
            bc_step4(qlds[wave], row, cb, ar512, p0, p1, p2, p3, q0, q1, q2, q3);
        }
        qs[sbase + 0][row] = q0; qs[sbase + 1][row] = q1;
        qs[sbase + 2][row] = q2; qs[sbase + 3][row] = q3;
    }
    __syncthreads();

    // C2: wave 0 scans 32 supers with A^8192 (readlane, 32 steps, tiny)
    if (wave == 0) {
        float ark[32];
        load_row32(A8K + batch * 1024, row, ark);
        float S = 0.f;
#pragma unroll 1
        for (int s = 0; s < NSUP; s++) {
            if (lane < 32) ss[s][row] = S;
            float addv = qs[s][row];
            S = mv_step_rl(ark, S, addv);
        }
    }
    __syncthreads();

    // C3: seeded sub-scans -> Sarr (all 64 lanes store their half's sups)
    {
        float q0 = ss[sbase + 0][row];
        float q1 = ss[sbase + 1][row];
        float q2 = ss[sbase + 2][row];
        float q3 = ss[sbase + 3][row];
#pragma unroll 1
        for (int j = 0; j < 16; j++) {
            Sarr[((size_t)(batch * NSUB + (sbase + 0) * 16 + j)) * 32 + row] = q0;
            Sarr[((size_t)(batch * NSUB + (sbase + 1) * 16 + j)) * 32 + row] = q1;
            Sarr[((size_t)(batch * NSUB + (sbase + 2) * 16 + j)) * 32 + row] = q2;
            Sarr[((size_t)(batch * NSUB + (sbase + 3) * 16 + j)) * 32 + row] = q3;
            if (j < 15) {
                float p0 = qe[(sbase + 0) * 16 + j][row];
                float p1 = qe[(sbase + 1) * 16 + j][row];
                float p2 = qe[(sbase + 2) * 16 + j][row];
                float p3 = qe[(sbase + 3) * 16 + j][row];
                bc_step4(qlds[wave], row, cb, ar512, p0, p1, p2, p3, q0, q1, q2, q3);
            }
        }
    }
}

// ---------------- K3: corrected-init re-run, write output ----------------
__global__ __launch_bounds__(64, 1) void k3_pass2(const float* __restrict__ audio,
                                                  const float* __restrict__ coefs,
                                                  const float* __restrict__ A64,
                                                  const float* __restrict__ P,
                                                  const float* __restrict__ Sarr,
                                                  float* __restrict__ out) {
    int blk   = blockIdx.x;
    int batch = blk >> 6;
    int grp   = blk & 63;
    int lane  = threadIdx.x;
    int row   = lane & 31;
    int half  = lane >> 5;
    int cb    = half * 4;

    __shared__ float xlds[GRP * XSTRIDE];   // audio in, y out (in place)
    __shared__ float plds[GRP][33];
    __shared__ float qlds[8 * 32];

    stage_audio(audio + (size_t)batch * T_LEN + (size_t)grp * GRP * L, xlds, lane);

    // coalesced P load (transposed layout) -> LDS
    {
        const float* pb = P + ((size_t)(batch * NG + grp)) * 2048;
        float pv[32];
#pragma unroll
        for (int s = 0; s < 32; s++) pv[s] = pb[s * 64 + lane];
#pragma unroll
        for (int s = 0; s < 32; s++) plds[lane][s] = pv[s];
    }
    __syncthreads();

    // 8 seeded chains (dual-half); overwrite plds[ch][row] with the chunk's
    // start state (read p first, then store current q = start state).
    {
        float ar[32];
        load_row32(A64 + batch * 1024, row, ar);
        const float* sp = Sarr + ((size_t)(batch * NSUB + grp * 8 + cb)) * 32 + row;
        float q0 = sp[0], q1 = sp[32], q2 = sp[64], q3 = sp[96];
#pragma unroll 1
        for (int j = 0; j < SUB; j++) {
            float p0 = plds[(cb + 0) * SUB + j][row];
            float p1 = plds[(cb + 1) * SUB + j][row];
            float p2 = plds[(cb + 2) * SUB + j][row];
            float p3 = plds[(cb + 3) * SUB + j][row];
            plds[(cb + 0) * SUB + j][row] = q0;
            plds[(cb + 1) * SUB + j][row] = q1;
            plds[(cb + 2) * SUB + j][row] = q2;
            plds[(cb + 3) * SUB + j][row] = q3;
            if (j < SUB - 1)
                bc_step4(qlds, row, cb, ar, p0, p1, p2, p3, q0, q1, q2, q3);
        }
    }
    __syncthreads();

    const float* cf = coefs + batch * 96;
    float c0[NB], c1[NB], c2[NB], c3[NB], c4[NB];
#pragma unroll
    for (int i = 0; i < NB; i++) {
        c0[i] = cf[i * 5 + 0]; c1[i] = cf[i * 5 + 1]; c2[i] = cf[i * 5 + 2];
        c3[i] = cf[i * 5 + 3]; c4[i] = cf[i * 5 + 4];
    }
    float ing  = cf[80];
    float outg = cf[81];

    float s1[NB], s2[NB];
#pragma unroll
    for (int i = 0; i < NB; i++) {
        s1[i] = plds[lane][2 * i];
        s2[i] = plds[lane][2 * i + 1];
    }

    float* xrow = &xlds[lane * XSTRIDE];
#pragma unroll 1
    for (int tt = 0; tt < 16; tt++) {
        float4 xv = *(const float4*)&xrow[tt * 4];
        float xs[4] = {xv.x, xv.y, xv.z, xv.w};
        float ys[4];
#pragma unroll
        for (int j = 0; j < 4; j++) {
            float u = ing * xs[j];
#pragma unroll
            for (int i = 0; i < NB; i++) {
                float y  = fmaf(c0[i], u, s1[i]);
                float n1 = fmaf(c1[i], u, s2[i]); n1 = fmaf(-c3[i], y, n1);
                float n2 = c2[i] * u;             n2 = fmaf(-c4[i], y, n2);
                s1[i] = n1; s2[i] = n2; u = y;
            }
            ys[j] = outg * u;
        }
        float4 yv; yv.x = ys[0]; yv.y = ys[1]; yv.z = ys[2]; yv.w = ys[3];
        *(float4*)&xrow[tt * 4] = yv;   // in-place: y overwrites consumed x
    }
    __syncthreads();

    // coalesced LDS -> global out
    {
        float4* g4 = (float4*)(out + (size_t)batch * T_LEN + (size_t)grp * GRP * L);
#pragma unroll
        for (int it = 0; it < 16; it++) {
            int idx = it * 64 + lane;
            int ch = idx >> 4, q = idx & 15;
            g4[it * 64 + lane] = *(const float4*)&xlds[ch * XSTRIDE + q * 4];
        }
    }
}

// ---------------- launcher ----------------
extern "C" void kernel_launch(void* const* d_in, const int* in_sizes, int n_in,
                              void* d_out, int out_size, void* d_ws, size_t ws_size,
                              hipStream_t stream) {
    const float* audio  = (const float*)d_in[0];
    const float* params = (const float*)d_in[1];
    float* out = (float*)d_out;
    float* ws  = (float*)d_ws;

    float* coefs = ws + OFF_COEF;
    float* A64   = ws + OFF_A64;
    float* A512  = ws + OFF_A512;
    float* A8K   = ws + OFF_A8K;
    float* Qend  = ws + OFF_QEND;
    float* Sarr  = ws + OFF_SARR;
    float* P     = ws + OFF_P;

    k0_setup<<<BATCH, 256, 0, stream>>>(params, coefs, A64, A512, A8K);
    k1_pass1<<<BATCH * NG, 64, 0, stream>>>(audio, coefs, A64, P, Qend);
    k2_combine<<<BATCH, 256, 0, stream>>>(A512, A8K, Qend, Sarr);
    k3_pass2<<<BATCH * NG, 64, 0, stream>>>(audio, coefs, A64, P, Sarr, out);
}